// Round 6
// baseline (293.883 us; speedup 1.0000x reference)
//
#include <hip/hip_runtime.h>
#include <math.h>

#define NPTS 300000
#define K 64
#define P 32
#define DETC 1e-16f
// ws floats: [0,64) N_k | [64,128) S_k | [128,2176) M[d][k] | [2176] int counter
#define WS_FLOATS (K + K + K * P)

#define NTHREADS 256
#define WPB 4
#define NTILES ((NPTS + 63) / 64)              // 4688 tiles of 64 points
#define NBLOCKS ((NTILES + WPB - 1) / WPB)     // 1172 -> exactly 1 tile per wave

#define PHS 36                                  // phi row stride (words): 32 phi + u + pad, 16B-aligned
#define GS  33                                  // gamma-chunk row stride: 32 + 1 pad (b32 ops, conflict-free)
#define WAVE_LDS (64 * PHS + 64 * GS)           // 4416 floats per wave
#define COMB_OFF (WPB * WAVE_LDS)               // 17664 floats
#define TOTAL_LDS (COMB_OFF + WS_FLOATS)        // 19840 floats = 79360 B -> 2 blocks/CU

#if __has_builtin(__builtin_amdgcn_exp2f)
#define EXP2(x) __builtin_amdgcn_exp2f(x)
#else
#define EXP2(x) __exp2f(x)
#endif

__device__ __forceinline__ float rlf(float x, int l) {
    return __int_as_float(__builtin_amdgcn_readlane(__float_as_int(x), l));
}

__global__ __launch_bounds__(NTHREADS, 2) void em_pass(
    const float* __restrict__ mu_phi,
    const float* __restrict__ log_cov_phi,
    const float* __restrict__ pi_k,
    const float* __restrict__ mu_k,
    const float* __restrict__ log_cov_k,
    float* __restrict__ gamma_out,
    float* __restrict__ out_tail,   // pi_new | mu_new | log_cov_new
    float* __restrict__ ws)
{
    __shared__ float smem[TOTAL_LDS];
    __shared__ int lastf;

    const int lane = threadIdx.x & 63;
    const int wave = threadIdx.x >> 6;
    const int tile = __builtin_amdgcn_readfirstlane(blockIdx.x * WPB + wave);

    float* phiT = smem + wave * WAVE_LDS;            // [64][PHS]
    float* G    = phiT + 64 * PHS;                   // [64][GS]
    float* comb = smem + COMB_OFF;                   // lN[64] | lS[64] | lM[64*32]

    const float LOG2E = 1.4426950408889634f;

    // ---- per-lane cluster constants (lane = cluster k), kept in VGPRs;
    //      broadcast later via v_readlane with compile-time lane index ----
    float icL, c2L;
    {
        const float4* mk4 = reinterpret_cast<const float4*>(mu_k + lane * P);
        float n2k = 0.f;
#pragma unroll
        for (int q = 0; q < 8; ++q) {
            float4 v = mk4[q];
            n2k = fmaf(v.x, v.x, n2k); n2k = fmaf(v.y, v.y, n2k);
            n2k = fmaf(v.z, v.z, n2k); n2k = fmaf(v.w, v.w, n2k);
        }
        const float lck  = log_cov_k[lane];
        const float icov = __expf(-lck);
        const float pik  = pi_k[lane];
        // E(base e) = icov*(dot - 0.5u) + 16*lcp + C ;  C = -0.5*icov*n2k - 16*lck + 16 + ln(pik)
        const float C = fmaf(-0.5f * icov, n2k, 16.f - 16.f * lck) + __logf(pik);
        icL = icov * LOG2E;
        c2L = C * LOG2E;
    }

    // zero block-combine region
    for (int idx = threadIdx.x; idx < WS_FLOATS; idx += NTHREADS) comb[idx] = 0.f;
    __syncthreads();

    const int gb  = tile * 64;
    const int cnt = (NPTS - gb < 64) ? (NPTS - gb) : 64;

    // ---- phase 1: lane = point. Own row -> VGPRs (8 independent float4 loads) ----
    const int ip = gb + ((lane < cnt) ? lane : (cnt - 1));   // clamp (valid data, no NaNs)
    float r[P];
    {
        const float4* r4 = reinterpret_cast<const float4*>(mu_phi + (size_t)ip * P);
#pragma unroll
        for (int q = 0; q < 8; ++q) {
            float4 v = r4[q];
            r[4*q+0] = v.x; r[4*q+1] = v.y; r[4*q+2] = v.z; r[4*q+3] = v.w;
        }
    }
    float n2 = 0.f;
#pragma unroll
    for (int d = 0; d < P; ++d) n2 = fmaf(r[d], r[d], n2);
    const float lcp = log_cov_phi[ip];
    const float u   = fmaf(32.f, __expf(lcp), n2);           // P*e^lcp + ||phi||^2
    const float b2  = 16.f * LOG2E * lcp;
    const float hu  = 0.5f * u;

    {   // write phi row + u to this wave's LDS tile (stride 36: b128-friendly, bank-uniform)
        float4* prow = reinterpret_cast<float4*>(phiT + lane * PHS);
#pragma unroll
        for (int q = 0; q < 8; ++q)
            prow[q] = make_float4(r[4*q+0], r[4*q+1], r[4*q+2], r[4*q+3]);
        phiT[lane * PHS + 32] = u;
    }

    // ---- phase 2: k-loop (fully unrolled). All-VALU, in-lane softmax sum. ----
    float w[K];
    float S = 0.f;
#pragma unroll
    for (int k = 0; k < K; ++k) {
        const float* mk = mu_k + k * P;                      // uniform -> s_load batches
        float d0 = 0.f, d1 = 0.f, d2 = 0.f, d3 = 0.f;
#pragma unroll
        for (int d = 0; d < P; d += 4) {
            d0 = fmaf(mk[d + 0], r[d + 0], d0);
            d1 = fmaf(mk[d + 1], r[d + 1], d1);
            d2 = fmaf(mk[d + 2], r[d + 2], d2);
            d3 = fmaf(mk[d + 3], r[d + 3], d3);
        }
        const float dot = (d0 + d1) + (d2 + d3);
        const float ic2 = rlf(icL, k);                       // constant-lane readlane -> SGPR
        const float bC  = b2 + rlf(c2L, k);
        const float E   = fmaf(ic2, dot - hu, bC);           // log2 w
        const float wk  = EXP2(E);
        w[k] = wk;
        S += wk;
    }
    const float rcpS = __builtin_amdgcn_rcpf(S);

    // ---- phase 3: two 32-k rounds: normalize -> G tile -> coalesced store + tail accumulate ----
    float accN = 0.f, accSv = 0.f;
    float accM[P];
    const int hh = lane >> 5;          // point-half handled by this lane in the tail
    const int jj = lane & 31;          // k-within-chunk handled by this lane

#pragma unroll
    for (int c = 0; c < 2; ++c) {
        // write normalized gamma chunk: lane i -> G[i][0..31]  (banks (i+j)%32: 2-way, free)
#pragma unroll
        for (int j = 0; j < 32; ++j)
            G[lane * GS + j] = fmaf(w[c * 32 + j], rcpS, DETC);

        accN = 0.f; accSv = 0.f;
#pragma unroll
        for (int d = 0; d < P; ++d) accM[d] = 0.f;

        // tail sweep: lane (hh,jj) covers k = c*32+jj, points p = hh*32 + pp
        for (int pp = 0; pp < 32; ++pp) {
            const int p = hh * 32 + pp;
            const bool valid = (p < cnt);
            const float gval = G[p * GS + jj];               // 2 addr-groups, 2-way, free
            const float uu   = phiT[p * PHS + 32];
            const float g    = valid ? gval : 0.f;
            if (valid)
                gamma_out[(size_t)(gb + p) * K + c * 32 + jj] = gval;  // 2x128B segments, coalesced
            accN  += g;
            accSv  = fmaf(g, uu, accSv);
            const float4* pr = reinterpret_cast<const float4*>(phiT + p * PHS);
#pragma unroll
            for (int q = 0; q < 8; ++q) {
                float4 v = pr[q];                            // uniform-ish broadcast (2 addrs)
                accM[4*q+0] = fmaf(g, v.x, accM[4*q+0]);
                accM[4*q+1] = fmaf(g, v.y, accM[4*q+1]);
                accM[4*q+2] = fmaf(g, v.z, accM[4*q+2]);
                accM[4*q+3] = fmaf(g, v.w, accM[4*q+3]);
            }
        }

        // flush this chunk's per-k partials (both point-halves add; LDS atomics combine)
        const int kk = c * 32 + jj;
        atomicAdd(&comb[kk], accN);
        atomicAdd(&comb[K + kk], accSv);
#pragma unroll
        for (int d = 0; d < P; ++d)
            atomicAdd(&comb[2 * K + d * K + kk], accM[d]);
    }

    __syncthreads();

    // ---- one set of global atomics per block ----
    for (int idx = threadIdx.x; idx < WS_FLOATS; idx += NTHREADS)
        atomicAdd(&ws[idx], comb[idx]);
    __syncthreads();

    // ---- decoupled finalize: last block computes the small outputs ----
    if (threadIdx.x == 0) {
        __threadfence();
        const int cdone = atomicAdd((int*)(ws + WS_FLOATS), 1);
        lastf = (cdone == NBLOCKS - 1);
    }
    __syncthreads();
    if (lastf) {
        __threadfence();
        const int k = threadIdx.x;
        if (k < K) {
            const float Nk = __hip_atomic_load(&ws[k],     __ATOMIC_RELAXED, __HIP_MEMORY_SCOPE_AGENT);
            const float Sk = __hip_atomic_load(&ws[K + k], __ATOMIC_RELAXED, __HIP_MEMORY_SCOPE_AGENT);
            float* pi_new      = out_tail;
            float* mu_new      = out_tail + K;
            float* log_cov_new = out_tail + K + K * P;

            pi_new[k] = Nk / (float)NPTS;
            const float invN = 1.f / Nk;
            float m2 = 0.f;
#pragma unroll
            for (int d = 0; d < P; ++d) {
                const float md = __hip_atomic_load(&ws[2 * K + d * K + k],
                                                   __ATOMIC_RELAXED, __HIP_MEMORY_SCOPE_AGENT) * invN;
                mu_new[k * P + d] = md;
                m2 = fmaf(md, md, m2);
            }
            const float cov = (Sk - Nk * m2) / (32.f * Nk);
            log_cov_new[k] = logf(cov);
        }
    }
}

extern "C" void kernel_launch(void* const* d_in, const int* in_sizes, int n_in,
                              void* d_out, int out_size, void* d_ws, size_t ws_size,
                              hipStream_t stream)
{
    const float* mu_phi      = (const float*)d_in[0];
    const float* log_cov_phi = (const float*)d_in[1];
    const float* pi_k        = (const float*)d_in[2];
    const float* mu_k        = (const float*)d_in[3];
    const float* log_cov_k   = (const float*)d_in[4];
    float* out = (float*)d_out;
    float* ws  = (float*)d_ws;

    hipMemsetAsync(ws, 0, (WS_FLOATS + 1) * sizeof(float), stream);
    em_pass<<<NBLOCKS, NTHREADS, 0, stream>>>(mu_phi, log_cov_phi, pi_k, mu_k,
                                              log_cov_k, out,
                                              out + (size_t)NPTS * K, ws);
}